// Round 1
// baseline (400.140 us; speedup 1.0000x reference)
//
#include <hip/hip_runtime.h>
#include <hip/hip_bf16.h>

typedef __attribute__((ext_vector_type(8))) short short8;
typedef __attribute__((ext_vector_type(4))) float f32x4;

__device__ __forceinline__ unsigned short f2bf(float f){
    unsigned u = __float_as_uint(f);
    unsigned r = (u + 0x7FFFu + ((u >> 16) & 1u)) >> 16;
    return (unsigned short)r;
}

// swizzled LDS byte offset for row-major bf16 tiles (stride 256B or 512B)
__device__ __forceinline__ unsigned swz(unsigned row, unsigned byte_in_row, unsigned stride){
    return (row * stride + byte_in_row) ^ ((row & 7u) << 4);
}

// ---- prep: transpose + bf16-convert weights ----
// W1T [256][128], W2T [128][256], W3T [512][256]  (all [n][k], bf16)
__global__ void prep_weights(const float* __restrict__ W1, const float* __restrict__ W2,
                             const float* __restrict__ W3,
                             unsigned short* __restrict__ W1T,
                             unsigned short* __restrict__ W2T,
                             unsigned short* __restrict__ W3T){
    int i = blockIdx.x * 256 + threadIdx.x;
    if (i < 32768){
        int n = i >> 7, k = i & 127;
        W1T[i] = f2bf(W1[k * 256 + n]);
    } else if (i < 65536){
        int j = i - 32768; int n = j >> 8, k = j & 255;
        W2T[j] = f2bf(W2[k * 128 + n]);
    } else if (i < 196608){
        int j = i - 65536; int n = j >> 8, k = j & 255;
        W3T[j] = f2bf(W3[k * 512 + n]);
    }
}

// ---- main: gather + f2 MLP + f MLP + heads, per-token logm/logv ----
__launch_bounds__(256, 2)
__global__ void main_kernel(const float* __restrict__ rho,
                            const float* __restrict__ c,
                            const float* __restrict__ w,
                            const int*  __restrict__ roads,
                            const unsigned short* __restrict__ W1T,
                            const float* __restrict__ b1,
                            const unsigned short* __restrict__ W2T,
                            const float* __restrict__ b2,
                            const unsigned short* __restrict__ W3T,
                            const float* __restrict__ b3,
                            const float* __restrict__ w21,
                            const float* __restrict__ b21s,
                            const float* __restrict__ w22,
                            const float* __restrict__ b22s,
                            float* __restrict__ pm,
                            float* __restrict__ pv)
{
    __shared__ __align__(16) unsigned char sXc[64 * 256];  // [64][128] bf16 gathered c
    __shared__ __align__(16) unsigned char sH2[64 * 512];  // [64][256] bf16 hidden of f2
    __shared__ __align__(16) unsigned char sX [64 * 512];  // [64][256] bf16 [rho | c_t]

    const int tid = threadIdx.x;
    const int t0  = blockIdx.x * 64;

    // stage: gather c rows (bf16) + rho tile (bf16)
    for (int u = tid; u < 64 * 32; u += 256){
        int row = u >> 5, ch = u & 31;   // ch = which float4 of the 128-dim row
        int road = roads[t0 + row];
        float4 v = make_float4(0.f, 0.f, 0.f, 0.f);
        if (road > 0)
            v = reinterpret_cast<const float4*>(c + (size_t)(road - 1) * 128)[ch];
        ushort4 h;
        h.x = f2bf(v.x); h.y = f2bf(v.y); h.z = f2bf(v.z); h.w = f2bf(v.w);
        *reinterpret_cast<ushort4*>(sXc + swz(row, ch * 8, 256)) = h;

        float4 rv = reinterpret_cast<const float4*>(rho + (size_t)(t0 + row) * 128)[ch];
        ushort4 rh;
        rh.x = f2bf(rv.x); rh.y = f2bf(rv.y); rh.z = f2bf(rv.z); rh.w = f2bf(rv.w);
        *reinterpret_cast<ushort4*>(sX + swz(row, ch * 8, 512)) = rh;
    }
    __syncthreads();

    const int lane = tid & 63, wv = tid >> 6;
    const int lr = lane & 15, lg = lane >> 4;
    const int arow = wv * 16 + lr;           // A-fragment row for this wave
    const int crow = wv * 16 + lg * 4;       // C-fragment base row

    // ---- GEMM1: H2 = selu(Xc @ W1 + b1), K=128, N=256 ----
    for (int nc = 0; nc < 16; ++nc){
        int n0 = nc * 16;
        f32x4 acc = {0.f, 0.f, 0.f, 0.f};
        #pragma unroll
        for (int kk = 0; kk < 4; ++kk){
            short8 a = *reinterpret_cast<const short8*>(sXc + swz(arow, kk * 64 + lg * 16, 256));
            short8 b = *reinterpret_cast<const short8*>(W1T + (n0 + lr) * 128 + kk * 32 + lg * 8);
            acc = __builtin_amdgcn_mfma_f32_16x16x32_bf16(a, b, acc, 0, 0, 0);
        }
        int n = n0 + lr;
        float bias = b1[n];
        #pragma unroll
        for (int r = 0; r < 4; ++r){
            float vv = acc[r] + bias;
            // selu: scale * (x>0 ? x : alpha*expm1(x)); scale*alpha = 1.7580993408473766
            vv = (vv > 0.f) ? 1.0507009873554805f * vv
                            : 1.7580993408473766f * expm1f(vv);
            *reinterpret_cast<unsigned short*>(sH2 + swz(crow + r, n * 2, 512)) = f2bf(vv);
        }
    }
    __syncthreads();

    // ---- GEMM2: c_t = H2 @ W2 + b2, K=256, N=128 -> sX[:,128:256] ----
    for (int nc = 0; nc < 8; ++nc){
        int n0 = nc * 16;
        f32x4 acc = {0.f, 0.f, 0.f, 0.f};
        #pragma unroll
        for (int kk = 0; kk < 8; ++kk){
            short8 a = *reinterpret_cast<const short8*>(sH2 + swz(arow, kk * 64 + lg * 16, 512));
            short8 b = *reinterpret_cast<const short8*>(W2T + (n0 + lr) * 256 + kk * 32 + lg * 8);
            acc = __builtin_amdgcn_mfma_f32_16x16x32_bf16(a, b, acc, 0, 0, 0);
        }
        int n = n0 + lr;
        float bias = b2[n];
        #pragma unroll
        for (int r = 0; r < 4; ++r){
            float vv = acc[r] + bias;
            *reinterpret_cast<unsigned short*>(sX + swz(crow + r, (128 + n) * 2, 512)) = f2bf(vv);
        }
    }
    __syncthreads();

    // ---- GEMM3 + heads: h1 = relu(X @ W3 + b3); logm/logv = h1 . w21/w22 ----
    float hm[4] = {0.f, 0.f, 0.f, 0.f};
    float hv_[4] = {0.f, 0.f, 0.f, 0.f};
    for (int nc = 0; nc < 32; ++nc){
        int n0 = nc * 16;
        f32x4 acc = {0.f, 0.f, 0.f, 0.f};
        #pragma unroll
        for (int kk = 0; kk < 8; ++kk){
            short8 a = *reinterpret_cast<const short8*>(sX + swz(arow, kk * 64 + lg * 16, 512));
            short8 b = *reinterpret_cast<const short8*>(W3T + (n0 + lr) * 256 + kk * 32 + lg * 8);
            acc = __builtin_amdgcn_mfma_f32_16x16x32_bf16(a, b, acc, 0, 0, 0);
        }
        int n = n0 + lr;
        float bias = b3[n];
        float wm = w21[n], wvv = w22[n];
        #pragma unroll
        for (int r = 0; r < 4; ++r){
            float h = fmaxf(acc[r] + bias, 0.f);
            hm[r]  += h * wm;
            hv_[r] += h * wvv;
        }
    }
    // reduce across the 16 lane-columns (same lg group holds same 4 rows)
    #pragma unroll
    for (int off = 1; off < 16; off <<= 1){
        #pragma unroll
        for (int r = 0; r < 4; ++r){
            hm[r]  += __shfl_xor(hm[r],  off, 64);
            hv_[r] += __shfl_xor(hv_[r], off, 64);
        }
    }
    if (lr == 0){
        float B21 = b21s[0], B22 = b22s[0];
        #pragma unroll
        for (int r = 0; r < 4; ++r){
            int t = t0 + crow + r;
            float lw = logf(w[t]);
            pm[t] = hm[r]  + B21 + lw;
            pv[t] = hv_[r] + B22 + 2.f * lw;
        }
    }
}

// ---- reduce: per-batch logsumexp + epilogue ----
__global__ void reduce_kernel(const float* __restrict__ pm, const float* __restrict__ pv,
                              const float* __restrict__ l, float* __restrict__ out){
    int b = blockIdx.x;
    int tid = threadIdx.x;
    const float* Pm = pm + (size_t)b * 2048;
    const float* Pv = pv + (size_t)b * 2048;

    float mm = -1e30f, mv = -1e30f;
    for (int i = tid; i < 2048; i += 256){
        mm = fmaxf(mm, Pm[i]);
        mv = fmaxf(mv, Pv[i]);
    }
    __shared__ float redm[4], redv[4];
    #pragma unroll
    for (int off = 32; off > 0; off >>= 1){
        mm = fmaxf(mm, __shfl_xor(mm, off, 64));
        mv = fmaxf(mv, __shfl_xor(mv, off, 64));
    }
    int wv = tid >> 6;
    if ((tid & 63) == 0){ redm[wv] = mm; redv[wv] = mv; }
    __syncthreads();
    mm = fmaxf(fmaxf(redm[0], redm[1]), fmaxf(redm[2], redm[3]));
    mv = fmaxf(fmaxf(redv[0], redv[1]), fmaxf(redv[2], redv[3]));

    float sm = 0.f, sv = 0.f;
    for (int i = tid; i < 2048; i += 256){
        sm += expf(Pm[i] - mm);
        sv += expf(Pv[i] - mv);
    }
    #pragma unroll
    for (int off = 32; off > 0; off >>= 1){
        sm += __shfl_xor(sm, off, 64);
        sv += __shfl_xor(sv, off, 64);
    }
    __shared__ float red2m[4], red2v[4];
    if ((tid & 63) == 0){ red2m[wv] = sm; red2v[wv] = sv; }
    __syncthreads();
    if (tid == 0){
        sm = red2m[0] + red2m[1] + red2m[2] + red2m[3];
        sv = red2v[0] + red2v[1] + red2v[2] + red2v[3];
        float lsem = mm + logf(sm);
        float lsev = mv + logf(sv);
        float ll = logf(l[b]);
        out[b]      = ll - lsem;
        out[64 + b] = ll - 3.f * lsem - lsev;
    }
}

extern "C" void kernel_launch(void* const* d_in, const int* in_sizes, int n_in,
                              void* d_out, int out_size, void* d_ws, size_t ws_size,
                              hipStream_t stream){
    const float* rho   = (const float*)d_in[0];
    const float* c     = (const float*)d_in[1];
    const float* w     = (const float*)d_in[2];
    const float* l     = (const float*)d_in[3];
    const int*   roads = (const int*)  d_in[4];
    const float* f2_W1 = (const float*)d_in[5];
    const float* f2_b1 = (const float*)d_in[6];
    const float* f2_W2 = (const float*)d_in[7];
    const float* f2_b2 = (const float*)d_in[8];
    const float* f_W1  = (const float*)d_in[9];
    const float* f_b1  = (const float*)d_in[10];
    const float* f_W21 = (const float*)d_in[11];
    const float* f_b21 = (const float*)d_in[12];
    const float* f_W22 = (const float*)d_in[13];
    const float* f_b22 = (const float*)d_in[14];

    unsigned char* ws = (unsigned char*)d_ws;
    unsigned short* W1T = (unsigned short*)(ws);                 // 65536 B
    unsigned short* W2T = (unsigned short*)(ws + 65536);         // 65536 B
    unsigned short* W3T = (unsigned short*)(ws + 131072);        // 262144 B
    float* pm = (float*)(ws + 393216);                           // 524288 B
    float* pv = (float*)(ws + 393216 + 524288);                  // 524288 B

    prep_weights<<<768, 256, 0, stream>>>(f2_W1, f2_W2, f_W1, W1T, W2T, W3T);
    main_kernel<<<2048, 256, 0, stream>>>(rho, c, w, roads,
                                          W1T, f2_b1, W2T, f2_b2, W3T, f_b1,
                                          f_W21, f_b21, f_W22, f_b22, pm, pv);
    reduce_kernel<<<64, 256, 0, stream>>>(pm, pv, l, (float*)d_out);
}

// Round 2
// 157.205 us; speedup vs baseline: 2.5453x; 2.5453x over previous
//
#include <hip/hip_runtime.h>
#include <hip/hip_bf16.h>

typedef __attribute__((ext_vector_type(8))) short short8;
typedef __attribute__((ext_vector_type(4))) float f32x4;

__device__ __forceinline__ unsigned short f2bf(float f){
    unsigned u = __float_as_uint(f);
    unsigned r = (u + 0x7FFFu + ((u >> 16) & 1u)) >> 16;
    return (unsigned short)r;
}

// swizzled LDS byte offset for row-major bf16 tiles (stride 256B or 512B)
__device__ __forceinline__ unsigned swz(unsigned row, unsigned byte_in_row, unsigned stride){
    return (row * stride + byte_in_row) ^ ((row & 7u) << 4);
}

// ---- prep: transpose + bf16-convert weights ----
// W1T [256][128], W2T [128][256], W3T [512][256]  (all [n][k], bf16)
__global__ void prep_weights(const float* __restrict__ W1, const float* __restrict__ W2,
                             const float* __restrict__ W3,
                             unsigned short* __restrict__ W1T,
                             unsigned short* __restrict__ W2T,
                             unsigned short* __restrict__ W3T){
    int i = blockIdx.x * 256 + threadIdx.x;
    if (i < 32768){
        int n = i >> 7, k = i & 127;
        W1T[i] = f2bf(W1[k * 256 + n]);
    } else if (i < 65536){
        int j = i - 32768; int n = j >> 8, k = j & 255;
        W2T[j] = f2bf(W2[k * 128 + n]);
    } else if (i < 196608){
        int j = i - 65536; int n = j >> 8, k = j & 255;
        W3T[j] = f2bf(W3[k * 512 + n]);
    }
}

// ---- main: gather + f2 MLP + f MLP + heads; waves split N, each wave does all 64 rows ----
__launch_bounds__(256, 2)
__global__ void main_kernel(const float* __restrict__ rho,
                            const float* __restrict__ c,
                            const float* __restrict__ w,
                            const int*  __restrict__ roads,
                            const unsigned short* __restrict__ W1T,
                            const float* __restrict__ b1,
                            const unsigned short* __restrict__ W2T,
                            const float* __restrict__ b2,
                            const unsigned short* __restrict__ W3T,
                            const float* __restrict__ b3,
                            const float* __restrict__ w21,
                            const float* __restrict__ b21s,
                            const float* __restrict__ w22,
                            const float* __restrict__ b22s,
                            float* __restrict__ pm,
                            float* __restrict__ pv)
{
    __shared__ __align__(16) unsigned char smem[81920];
    unsigned char* sXc = smem;            // [64][128] bf16 gathered c (16384 B)
    unsigned char* sH2 = smem + 16384;    // [64][256] bf16 f2 hidden  (32768 B)
    unsigned char* sX  = smem + 49152;    // [64][256] bf16 [rho|c_t]  (32768 B)
    float* sPm = (float*)smem;            // head partials, reuse sXc region after GEMM1
    float* sPv = (float*)(smem + 4096);

    const int tid = threadIdx.x;
    const int t0  = blockIdx.x * 64;

    // stage: gather c rows (bf16) + rho tile (bf16)
    for (int u = tid; u < 64 * 32; u += 256){
        int row = u >> 5, ch = u & 31;
        int road = roads[t0 + row];
        float4 v = make_float4(0.f, 0.f, 0.f, 0.f);
        if (road > 0)
            v = reinterpret_cast<const float4*>(c + (size_t)(road - 1) * 128)[ch];
        ushort4 h;
        h.x = f2bf(v.x); h.y = f2bf(v.y); h.z = f2bf(v.z); h.w = f2bf(v.w);
        *reinterpret_cast<ushort4*>(sXc + swz(row, ch * 8, 256)) = h;

        float4 rv = reinterpret_cast<const float4*>(rho + (size_t)(t0 + row) * 128)[ch];
        ushort4 rh;
        rh.x = f2bf(rv.x); rh.y = f2bf(rv.y); rh.z = f2bf(rv.z); rh.w = f2bf(rv.w);
        *reinterpret_cast<ushort4*>(sX + swz(row, ch * 8, 512)) = rh;
    }
    __syncthreads();

    const int lane = tid & 63, wv = tid >> 6;
    const int lr = lane & 15, lg = lane >> 4;

    // ---- GEMM1: H2 = selu(Xc @ W1 + b1), K=128, N=256; wave wv owns n in [wv*64, wv*64+64) ----
    #pragma unroll
    for (int nc = 0; nc < 4; ++nc){
        const int n = wv * 64 + nc * 16 + lr;
        short8 b[4];
        #pragma unroll
        for (int kk = 0; kk < 4; ++kk)
            b[kk] = *reinterpret_cast<const short8*>(W1T + n * 128 + kk * 32 + lg * 8);
        f32x4 acc[4] = {{0.f,0.f,0.f,0.f},{0.f,0.f,0.f,0.f},{0.f,0.f,0.f,0.f},{0.f,0.f,0.f,0.f}};
        #pragma unroll
        for (int kk = 0; kk < 4; ++kk){
            #pragma unroll
            for (int mt = 0; mt < 4; ++mt){
                short8 a = *reinterpret_cast<const short8*>(sXc + swz(mt * 16 + lr, kk * 64 + lg * 16, 256));
                acc[mt] = __builtin_amdgcn_mfma_f32_16x16x32_bf16(a, b[kk], acc[mt], 0, 0, 0);
            }
        }
        float bias = b1[n];
        #pragma unroll
        for (int mt = 0; mt < 4; ++mt){
            #pragma unroll
            for (int r = 0; r < 4; ++r){
                float vv = acc[mt][r] + bias;
                vv = (vv > 0.f) ? 1.0507009873554805f * vv
                                : 1.7580993408473766f * expm1f(vv);
                *reinterpret_cast<unsigned short*>(sH2 + swz(mt * 16 + lg * 4 + r, n * 2, 512)) = f2bf(vv);
            }
        }
    }
    __syncthreads();

    // ---- GEMM2: c_t = H2 @ W2 + b2, K=256, N=128; wave wv owns n in [wv*32, wv*32+32) ----
    #pragma unroll
    for (int nc = 0; nc < 2; ++nc){
        const int n = wv * 32 + nc * 16 + lr;
        short8 b[8];
        #pragma unroll
        for (int kk = 0; kk < 8; ++kk)
            b[kk] = *reinterpret_cast<const short8*>(W2T + n * 256 + kk * 32 + lg * 8);
        f32x4 acc[4] = {{0.f,0.f,0.f,0.f},{0.f,0.f,0.f,0.f},{0.f,0.f,0.f,0.f},{0.f,0.f,0.f,0.f}};
        #pragma unroll
        for (int kk = 0; kk < 8; ++kk){
            #pragma unroll
            for (int mt = 0; mt < 4; ++mt){
                short8 a = *reinterpret_cast<const short8*>(sH2 + swz(mt * 16 + lr, kk * 64 + lg * 16, 512));
                acc[mt] = __builtin_amdgcn_mfma_f32_16x16x32_bf16(a, b[kk], acc[mt], 0, 0, 0);
            }
        }
        float bias = b2[n];
        #pragma unroll
        for (int mt = 0; mt < 4; ++mt){
            #pragma unroll
            for (int r = 0; r < 4; ++r){
                float vv = acc[mt][r] + bias;
                *reinterpret_cast<unsigned short*>(sX + swz(mt * 16 + lg * 4 + r, (128 + n) * 2, 512)) = f2bf(vv);
            }
        }
    }
    __syncthreads();

    // ---- GEMM3 + heads: h1 = relu(X @ W3 + b3); wave wv owns n in [wv*128, wv*128+128) ----
    float hm[4][4] = {};
    float hv[4][4] = {};
    #pragma unroll 2
    for (int nc = 0; nc < 8; ++nc){
        const int n = wv * 128 + nc * 16 + lr;
        short8 b[8];
        #pragma unroll
        for (int kk = 0; kk < 8; ++kk)
            b[kk] = *reinterpret_cast<const short8*>(W3T + n * 256 + kk * 32 + lg * 8);
        f32x4 acc[4] = {{0.f,0.f,0.f,0.f},{0.f,0.f,0.f,0.f},{0.f,0.f,0.f,0.f},{0.f,0.f,0.f,0.f}};
        #pragma unroll
        for (int kk = 0; kk < 8; ++kk){
            #pragma unroll
            for (int mt = 0; mt < 4; ++mt){
                short8 a = *reinterpret_cast<const short8*>(sX + swz(mt * 16 + lr, kk * 64 + lg * 16, 512));
                acc[mt] = __builtin_amdgcn_mfma_f32_16x16x32_bf16(a, b[kk], acc[mt], 0, 0, 0);
            }
        }
        float bias = b3[n];
        float wm = w21[n], wvv = w22[n];
        #pragma unroll
        for (int mt = 0; mt < 4; ++mt){
            #pragma unroll
            for (int r = 0; r < 4; ++r){
                float h = fmaxf(acc[mt][r] + bias, 0.f);
                hm[mt][r] += h * wm;
                hv[mt][r] += h * wvv;
            }
        }
    }
    // reduce across the 16 n-lanes (lr); lanes differing only in bits 0..3
    #pragma unroll
    for (int off = 1; off < 16; off <<= 1){
        #pragma unroll
        for (int mt = 0; mt < 4; ++mt){
            #pragma unroll
            for (int r = 0; r < 4; ++r){
                hm[mt][r] += __shfl_xor(hm[mt][r], off, 64);
                hv[mt][r] += __shfl_xor(hv[mt][r], off, 64);
            }
        }
    }
    if (lr == 0){
        #pragma unroll
        for (int mt = 0; mt < 4; ++mt){
            #pragma unroll
            for (int r = 0; r < 4; ++r){
                int row = mt * 16 + lg * 4 + r;
                sPm[wv * 64 + row] = hm[mt][r];
                sPv[wv * 64 + row] = hv[mt][r];
            }
        }
    }
    __syncthreads();
    if (tid < 64){
        float B21 = b21s[0], B22 = b22s[0];
        float m_ = sPm[tid] + sPm[64 + tid] + sPm[128 + tid] + sPm[192 + tid] + B21;
        float v_ = sPv[tid] + sPv[64 + tid] + sPv[128 + tid] + sPv[192 + tid] + B22;
        int t = t0 + tid;
        float lw = logf(w[t]);
        pm[t] = m_ + lw;
        pv[t] = v_ + 2.f * lw;
    }
}

// ---- reduce: per-batch logsumexp + epilogue ----
__global__ void reduce_kernel(const float* __restrict__ pm, const float* __restrict__ pv,
                              const float* __restrict__ l, float* __restrict__ out){
    int b = blockIdx.x;
    int tid = threadIdx.x;
    const float* Pm = pm + (size_t)b * 2048;
    const float* Pv = pv + (size_t)b * 2048;

    float mm = -1e30f, mv = -1e30f;
    for (int i = tid; i < 2048; i += 256){
        mm = fmaxf(mm, Pm[i]);
        mv = fmaxf(mv, Pv[i]);
    }
    __shared__ float redm[4], redv[4];
    #pragma unroll
    for (int off = 32; off > 0; off >>= 1){
        mm = fmaxf(mm, __shfl_xor(mm, off, 64));
        mv = fmaxf(mv, __shfl_xor(mv, off, 64));
    }
    int wv = tid >> 6;
    if ((tid & 63) == 0){ redm[wv] = mm; redv[wv] = mv; }
    __syncthreads();
    mm = fmaxf(fmaxf(redm[0], redm[1]), fmaxf(redm[2], redm[3]));
    mv = fmaxf(fmaxf(redv[0], redv[1]), fmaxf(redv[2], redv[3]));

    float sm = 0.f, sv = 0.f;
    for (int i = tid; i < 2048; i += 256){
        sm += expf(Pm[i] - mm);
        sv += expf(Pv[i] - mv);
    }
    #pragma unroll
    for (int off = 32; off > 0; off >>= 1){
        sm += __shfl_xor(sm, off, 64);
        sv += __shfl_xor(sv, off, 64);
    }
    __shared__ float red2m[4], red2v[4];
    if ((tid & 63) == 0){ red2m[wv] = sm; red2v[wv] = sv; }
    __syncthreads();
    if (tid == 0){
        sm = red2m[0] + red2m[1] + red2m[2] + red2m[3];
        sv = red2v[0] + red2v[1] + red2v[2] + red2v[3];
        float lsem = mm + logf(sm);
        float lsev = mv + logf(sv);
        float ll = logf(l[b]);
        out[b]      = ll - lsem;
        out[64 + b] = ll - 3.f * lsem - lsev;
    }
}

extern "C" void kernel_launch(void* const* d_in, const int* in_sizes, int n_in,
                              void* d_out, int out_size, void* d_ws, size_t ws_size,
                              hipStream_t stream){
    const float* rho   = (const float*)d_in[0];
    const float* c     = (const float*)d_in[1];
    const float* w     = (const float*)d_in[2];
    const float* l     = (const float*)d_in[3];
    const int*   roads = (const int*)  d_in[4];
    const float* f2_W1 = (const float*)d_in[5];
    const float* f2_b1 = (const float*)d_in[6];
    const float* f2_W2 = (const float*)d_in[7];
    const float* f2_b2 = (const float*)d_in[8];
    const float* f_W1  = (const float*)d_in[9];
    const float* f_b1  = (const float*)d_in[10];
    const float* f_W21 = (const float*)d_in[11];
    const float* f_b21 = (const float*)d_in[12];
    const float* f_W22 = (const float*)d_in[13];
    const float* f_b22 = (const float*)d_in[14];

    unsigned char* ws = (unsigned char*)d_ws;
    unsigned short* W1T = (unsigned short*)(ws);                 // 65536 B
    unsigned short* W2T = (unsigned short*)(ws + 65536);         // 65536 B
    unsigned short* W3T = (unsigned short*)(ws + 131072);        // 262144 B
    float* pm = (float*)(ws + 393216);                           // 524288 B
    float* pv = (float*)(ws + 393216 + 524288);                  // 524288 B

    prep_weights<<<768, 256, 0, stream>>>(f2_W1, f2_W2, f_W1, W1T, W2T, W3T);
    main_kernel<<<2048, 256, 0, stream>>>(rho, c, w, roads,
                                          W1T, f2_b1, W2T, f2_b2, W3T, f_b1,
                                          f_W21, f_b21, f_W22, f_b22, pm, pv);
    reduce_kernel<<<64, 256, 0, stream>>>(pm, pv, l, (float*)d_out);
}